// Round 1
// baseline (17604.909 us; speedup 1.0000x reference)
//
#include <hip/hip_runtime.h>
#include <hip/hip_bf16.h>

// ---------------------------------------------------------------------------
// AutoregressiveBeamDecoder: B=256, T=128, D=512, H=1024, NB=64, HH=8
// Round 1: fp32 correctness baseline.
//  - bpart[p,j] = beam_embed[p] @ W_in[:, D:]^T        (precomputed, 64x1024)
//  - cin[t][b,j] = ctx[b,t] @ W_in[:, :D]^T + b_in     (per-step, ring buf)
//  - octx[b,i]  = ctx[b,t] @ W_o1[:, H:]^T + b_o1      (per-step)
//  - LN folded into o-GEMM via u,v vectors and hg = h_new * ln_g
// ---------------------------------------------------------------------------

#define TS 68          // padded LDS row stride (floats); 68*4 = 272 B = 17*16
constexpr int SZ = 262144;   // 256*1024
constexpr int TT = 128;      // T
constexpr int LDA_CTX = 65536; // T*D

// ---------------- fp32 tiled GEMM core: C[b,n] = sum_k A[b,k] * W[n,k] -----

__device__ __forceinline__ void gemm_tile64(
    const float* __restrict__ A, int lda, int Mlim, int b0,
    const float* __restrict__ W, int ldw, int n0, int K,
    float* At, float* Wt, float acc[4][4])
{
    const int tid = threadIdx.x;
    const int tx = tid & 15, ty = tid >> 4;
    const int r = tid >> 2, c0 = (tid & 3) << 2;
    for (int k0 = 0; k0 < K; k0 += 16) {
        float4 av = make_float4(0.f, 0.f, 0.f, 0.f);
        if (b0 + r < Mlim)
            av = *(const float4*)(A + (size_t)(b0 + r) * lda + k0 + c0);
        float4 wv = *(const float4*)(W + (size_t)(n0 + r) * ldw + k0 + c0);
        __syncthreads();
        At[(c0+0)*TS + r] = av.x; At[(c0+1)*TS + r] = av.y;
        At[(c0+2)*TS + r] = av.z; At[(c0+3)*TS + r] = av.w;
        Wt[(c0+0)*TS + r] = wv.x; Wt[(c0+1)*TS + r] = wv.y;
        Wt[(c0+2)*TS + r] = wv.z; Wt[(c0+3)*TS + r] = wv.w;
        __syncthreads();
#pragma unroll
        for (int kk = 0; kk < 16; ++kk) {
            float4 a = *(const float4*)(At + kk*TS + ty*4);
            float4 w = *(const float4*)(Wt + kk*TS + tx*4);
            acc[0][0] += a.x*w.x; acc[0][1] += a.x*w.y; acc[0][2] += a.x*w.z; acc[0][3] += a.x*w.w;
            acc[1][0] += a.y*w.x; acc[1][1] += a.y*w.y; acc[1][2] += a.y*w.z; acc[1][3] += a.y*w.w;
            acc[2][0] += a.z*w.x; acc[2][1] += a.z*w.y; acc[2][2] += a.z*w.z; acc[2][3] += a.z*w.w;
            acc[3][0] += a.w*w.x; acc[3][1] += a.w*w.y; acc[3][2] += a.w*w.z; acc[3][3] += a.w*w.w;
        }
    }
}

// -------------------- setup kernels ----------------------------------------

// ctx_global mean + hist_emb mean -> A0 = [cg | he]; also prev0
__global__ void pre0_kernel(const float* __restrict__ ctx, const int* __restrict__ bh,
                            const float* __restrict__ be, float* __restrict__ A0,
                            int* __restrict__ prev)
{
    int b = blockIdx.x, tid = threadIdx.x; // blockDim 512
    float s = 0.f;
    for (int t = 0; t < TT; ++t) s += ctx[(size_t)b * LDA_CTX + t * 512 + tid];
    A0[b * 1024 + tid] = s * (1.f / 128.f);
    float s2 = 0.f;
    for (int i = 0; i < 8; ++i) s2 += be[bh[b * 8 + i] * 512 + tid];
    A0[b * 1024 + 512 + tid] = s2 * 0.125f;
    if (tid == 0) prev[b] = bh[b * 8 + 7];
}

__global__ void copy_gb_kernel(const float* g, const float* bb, float* gb)
{
    int idx = blockIdx.x * 256 + threadIdx.x; // 8 blocks
    if (idx < 1024) gb[idx] = g[idx];
    else            gb[idx] = bb[idx - 1024];
}

__global__ void wo2t_kernel(const float* __restrict__ W_o2, float* __restrict__ Wo2t)
{
    int idx = blockIdx.x * 256 + threadIdx.x; // 256 blocks -> 65536
    int k = idx >> 6, n = idx & 63;
    Wo2t[idx] = W_o2[n * 1024 + k];
}

// generic small GEMM (M may be < 64); act: 0 none, 1 tanh
__global__ void gemm64_kernel(const float* __restrict__ A, int lda, int M,
                              const float* __restrict__ W, int ldw, int K,
                              const float* __restrict__ bias,
                              float* __restrict__ C, int ldc, int act)
{
    __shared__ __align__(16) float At[16 * TS];
    __shared__ __align__(16) float Wt[16 * TS];
    float acc[4][4] = {};
    int b0 = blockIdx.x * 64, n0 = blockIdx.y * 64;
    gemm_tile64(A, lda, M, b0, W, ldw, n0, K, At, Wt, acc);
    int tx = threadIdx.x & 15, ty = threadIdx.x >> 4;
#pragma unroll
    for (int i = 0; i < 4; ++i) {
        int b = b0 + ty * 4 + i;
        if (b >= M) continue;
#pragma unroll
        for (int j = 0; j < 4; ++j) {
            int n = n0 + tx * 4 + j;
            float v = acc[i][j] + (bias ? bias[n] : 0.f);
            if (act == 1) v = tanhf(v);
            C[(size_t)b * ldc + n] = v;
        }
    }
}

__global__ void xbuild0_kernel(const float* __restrict__ cin0, const float* __restrict__ bpart,
                               const int* __restrict__ prev, float* __restrict__ x)
{
    int b = blockIdx.x, tid = threadIdx.x;
    int pb = prev[b];
    const float* cn = cin0 + (size_t)b * 1024;
    const float* bp = bpart + (size_t)pb * 1024;
#pragma unroll
    for (int jj = 0; jj < 4; ++jj) {
        int j = jj * 256 + tid;
        x[(size_t)b * 1024 + j] = fmaxf(cn[j] + bp[j], 0.f);
    }
}

// -------------------- per-step kernels -------------------------------------

// grid (4,16,8): z 0..5 -> gate sub-GEMMs (g = z%3 in {r,z,n}, src = z/3 in {x,h})
//                z 6    -> cin[t+1],  z 7 -> octx[t]
__global__ void step_gemms_kernel(
    const float* __restrict__ x, const float* __restrict__ hBase,
    const float* __restrict__ ctx,
    const float* __restrict__ Wih, const float* __restrict__ Whh,
    const float* __restrict__ Win, const float* __restrict__ Wo1,
    const float* __restrict__ b_in, const float* __restrict__ b_o1,
    float* __restrict__ g6, float* __restrict__ cinBase, float* __restrict__ octx,
    int t)
{
    __shared__ __align__(16) float At[16 * TS];
    __shared__ __align__(16) float Wt[16 * TS];
    float acc[4][4] = {};
    const int z = blockIdx.z, b0 = blockIdx.x * 64, n0 = blockIdx.y * 64;
    const float *A, *W, *bias = nullptr;
    float* C;
    int lda, ldw, K;
    if (z < 6) {
        int g = z % 3, s = z / 3;
        A = s ? (hBase + (size_t)(t & 1) * SZ) : x;
        lda = 1024;
        W = (s ? Whh : Wih) + (size_t)(g * 1024) * 1024;
        ldw = 1024; K = 1024;
        C = g6 + (size_t)z * SZ;
    } else if (z == 6) {
        if (t + 1 >= TT) return;
        A = ctx + (size_t)(t + 1) * 512; lda = LDA_CTX;
        W = Win; ldw = 1024; K = 512; bias = b_in;
        C = cinBase + (size_t)((t + 1) & 1) * SZ;
    } else {
        A = ctx + (size_t)t * 512; lda = LDA_CTX;
        W = Wo1 + 1024; ldw = 1536; K = 512; bias = b_o1;
        C = octx;
    }
    gemm_tile64(A, lda, 256, b0, W, ldw, n0, K, At, Wt, acc);
    int tx = threadIdx.x & 15, ty = threadIdx.x >> 4;
#pragma unroll
    for (int i = 0; i < 4; ++i) {
        int b = b0 + ty * 4 + i;
#pragma unroll
        for (int j = 0; j < 4; ++j) {
            int n = n0 + tx * 4 + j;
            float v = acc[i][j];
            if (bias) v += bias[n];
            C[(size_t)b * 1024 + n] = v;
        }
    }
}

// GRU combine + LN stats; one block per batch row
__global__ void gru_ln_kernel(const float* __restrict__ g6,
                              const float* __restrict__ b_ih, const float* __restrict__ b_hh,
                              float* __restrict__ hBase, const float* __restrict__ ln_g,
                              float* __restrict__ hg, float* __restrict__ mbuf,
                              float* __restrict__ isbuf, int t)
{
    __shared__ float rs[256], rq[256];
    int b = blockIdx.x, tid = threadIdx.x;
    const float* hc = hBase + (size_t)(t & 1) * SZ + (size_t)b * 1024;
    float* hnx = hBase + (size_t)((t + 1) & 1) * SZ + (size_t)b * 1024;
    float s = 0.f, q = 0.f;
#pragma unroll
    for (int jj = 0; jj < 4; ++jj) {
        int j = jj * 256 + tid;
        size_t base = (size_t)b * 1024 + j;
        float xr = g6[0 * (size_t)SZ + base] + b_ih[j];
        float xz = g6[1 * (size_t)SZ + base] + b_ih[1024 + j];
        float xn = g6[2 * (size_t)SZ + base] + b_ih[2048 + j];
        float hr = g6[3 * (size_t)SZ + base] + b_hh[j];
        float hz = g6[4 * (size_t)SZ + base] + b_hh[1024 + j];
        float hn = g6[5 * (size_t)SZ + base] + b_hh[2048 + j];
        float r = 1.f / (1.f + expf(-(xr + hr)));
        float z = 1.f / (1.f + expf(-(xz + hz)));
        float nn = tanhf(xn + r * hn);
        float ho = hc[j];
        float hv = (1.f - z) * nn + z * ho;
        hnx[j] = hv;
        hg[base] = hv * ln_g[j];
        s += hv; q += hv * hv;
    }
    rs[tid] = s; rq[tid] = q;
    __syncthreads();
    for (int st = 128; st; st >>= 1) {
        if (tid < st) { rs[tid] += rs[tid + st]; rq[tid] += rq[tid + st]; }
        __syncthreads();
    }
    if (tid == 0) {
        float m = rs[0] * (1.f / 1024.f);
        float var = rq[0] * (1.f / 1024.f) - m * m;
        mbuf[b] = m;
        isbuf[b] = rsqrtf(var + 1e-5f);
    }
}

// o-GEMM with folded LN epilogue; grid (8,16), 32x64 tiles
__global__ void kb_kernel(const float* __restrict__ hg, const float* __restrict__ Wo1,
                          const float* __restrict__ uv, const float* __restrict__ octx,
                          const float* __restrict__ mbuf, const float* __restrict__ isbuf,
                          float* __restrict__ o)
{
    __shared__ __align__(16) float At[16 * TS];
    __shared__ __align__(16) float Wt[16 * TS];
    float acc[2][4] = {};
    const int b0 = blockIdx.x * 32, n0 = blockIdx.y * 64;
    const int tid = threadIdx.x, tx = tid & 15, ty = tid >> 4;
    const int r = tid >> 2, c0 = (tid & 3) << 2;
    for (int k0 = 0; k0 < 1024; k0 += 16) {
        float4 av = make_float4(0.f, 0.f, 0.f, 0.f);
        if (r < 32) av = *(const float4*)(hg + (size_t)(b0 + r) * 1024 + k0 + c0);
        float4 wv = *(const float4*)(Wo1 + (size_t)(n0 + r) * 1536 + k0 + c0);
        __syncthreads();
        At[(c0+0)*TS + r] = av.x; At[(c0+1)*TS + r] = av.y;
        At[(c0+2)*TS + r] = av.z; At[(c0+3)*TS + r] = av.w;
        Wt[(c0+0)*TS + r] = wv.x; Wt[(c0+1)*TS + r] = wv.y;
        Wt[(c0+2)*TS + r] = wv.z; Wt[(c0+3)*TS + r] = wv.w;
        __syncthreads();
#pragma unroll
        for (int kk = 0; kk < 16; ++kk) {
            float2 a = *(const float2*)(At + kk*TS + ty*2);
            float4 w = *(const float4*)(Wt + kk*TS + tx*4);
            acc[0][0] += a.x*w.x; acc[0][1] += a.x*w.y; acc[0][2] += a.x*w.z; acc[0][3] += a.x*w.w;
            acc[1][0] += a.y*w.x; acc[1][1] += a.y*w.y; acc[1][2] += a.y*w.z; acc[1][3] += a.y*w.w;
        }
    }
#pragma unroll
    for (int i = 0; i < 2; ++i) {
        int b = b0 + ty * 2 + i;
        float m = mbuf[b], is = isbuf[b];
#pragma unroll
        for (int j = 0; j < 4; ++j) {
            int n = n0 + tx * 4 + j;
            float v = (acc[i][j] - m * uv[n]) * is + uv[1024 + n] + octx[(size_t)b * 1024 + n];
            o[(size_t)b * 1024 + n] = fmaxf(v, 0.f);
        }
    }
}

// logits + argmax + next-step x build; one block per batch row
__global__ void kc_kernel(const float* __restrict__ o, const float* __restrict__ Wo2t,
                          const float* __restrict__ b_o2, const float* __restrict__ cinBase,
                          const float* __restrict__ bpart, float* __restrict__ x,
                          int* __restrict__ prev, float* __restrict__ out, int t)
{
    __shared__ __align__(16) float os[1024];
    __shared__ float red[4][64];
    __shared__ int sidx;
    int b = blockIdx.x, tid = threadIdx.x;
    const float* orow = o + (size_t)b * 1024;
    *(float4*)&os[tid * 4] = *(const float4*)&orow[tid * 4];
    __syncthreads();
    int n = tid & 63, seg = tid >> 6;
    float p = 0.f;
    int k0 = seg * 256;
#pragma unroll 8
    for (int k = 0; k < 256; ++k) p += os[k0 + k] * Wo2t[(size_t)(k0 + k) * 64 + n];
    red[seg][n] = p;
    __syncthreads();
    if (tid < 64) {
        float lg = red[0][tid] + red[1][tid] + red[2][tid] + red[3][tid] + b_o2[tid];
        out[((size_t)b * TT + t) * 64 + tid] = lg;
        float v = lg; int idx = tid;
        for (int off = 32; off; off >>= 1) {
            float ov = __shfl_xor(v, off);
            int oi = __shfl_xor(idx, off);
            if (ov > v || (ov == v && oi < idx)) { v = ov; idx = oi; }
        }
        if (tid == 0) { prev[b] = idx; sidx = idx; }
    }
    __syncthreads();
    if (t + 1 < TT) {
        int pb = sidx;
        const float* cn = cinBase + (size_t)((t + 1) & 1) * SZ + (size_t)b * 1024;
        const float* bp = bpart + (size_t)pb * 1024;
#pragma unroll
        for (int jj = 0; jj < 4; ++jj) {
            int j = jj * 256 + tid;
            x[(size_t)b * 1024 + j] = fmaxf(cn[j] + bp[j], 0.f);
        }
    }
}

// ---------------------------------------------------------------------------

extern "C" void kernel_launch(void* const* d_in, const int* in_sizes, int n_in,
                              void* d_out, int out_size, void* d_ws, size_t ws_size,
                              hipStream_t stream)
{
    const float* ctx    = (const float*)d_in[0];
    const int*   bh     = (const int*)d_in[1];
    const float* be     = (const float*)d_in[2];
    const float* W_in   = (const float*)d_in[3];
    const float* b_in   = (const float*)d_in[4];
    const float* W_init = (const float*)d_in[5];
    const float* b_init = (const float*)d_in[6];
    const float* W_ih   = (const float*)d_in[7];
    const float* b_ih   = (const float*)d_in[8];
    const float* W_hh   = (const float*)d_in[9];
    const float* b_hh   = (const float*)d_in[10];
    const float* ln_g   = (const float*)d_in[11];
    const float* ln_b   = (const float*)d_in[12];
    const float* W_o1   = (const float*)d_in[13];
    const float* b_o1   = (const float*)d_in[14];
    const float* W_o2   = (const float*)d_in[15];
    const float* b_o2   = (const float*)d_in[16];
    float* out = (float*)d_out;
    float* ws  = (float*)d_ws;

    float* A0    = ws;                    // 256x1024
    float* hbuf  = ws + 1 * (size_t)SZ;   // 2 slots
    float* hg    = ws + 3 * (size_t)SZ;
    float* x     = ws + 4 * (size_t)SZ;
    float* cin   = ws + 5 * (size_t)SZ;   // 2 slots
    float* octx  = ws + 7 * (size_t)SZ;
    float* g6    = ws + 8 * (size_t)SZ;   // 6 slots
    float* obuf  = ws + 14 * (size_t)SZ;
    float* bpart = ws + 15 * (size_t)SZ;  // 64x1024
    float* uvv   = bpart + 65536;         // 2x1024 (u then v)
    float* gb    = uvv + 2048;            // 2x1024 ([ln_g; ln_b])
    float* Wo2t  = gb + 2048;             // 1024x64
    float* mbuf  = Wo2t + 65536;          // 256
    float* isbuf = mbuf + 256;            // 256
    int*   prev  = (int*)(isbuf + 256);   // 256

    // ---- setup ----
    pre0_kernel<<<256, 512, 0, stream>>>(ctx, bh, be, A0, prev);
    copy_gb_kernel<<<8, 256, 0, stream>>>(ln_g, ln_b, gb);
    wo2t_kernel<<<256, 256, 0, stream>>>(W_o2, Wo2t);
    // h0 = tanh(A0 @ W_init^T + b_init) -> h slot 0
    gemm64_kernel<<<dim3(4, 16), 256, 0, stream>>>(A0, 1024, 256, W_init, 1024, 1024,
                                                   b_init, hbuf, 1024, 1);
    // bpart = beam_embed @ W_in[:, D:]^T (no bias)
    gemm64_kernel<<<dim3(1, 16), 256, 0, stream>>>(be, 512, 64, W_in + 512, 1024, 512,
                                                   nullptr, bpart, 1024, 0);
    // [u; v] = [ln_g; ln_b] @ W_o1[:, :H]^T
    gemm64_kernel<<<dim3(1, 16), 256, 0, stream>>>(gb, 1024, 2, W_o1, 1536, 1024,
                                                   nullptr, uvv, 1024, 0);
    // cin[0] = ctx[:,0,:] @ W_in[:, :D]^T + b_in
    gemm64_kernel<<<dim3(4, 16), 256, 0, stream>>>(ctx, LDA_CTX, 256, W_in, 1024, 512,
                                                   b_in, cin, 1024, 0);
    xbuild0_kernel<<<256, 256, 0, stream>>>(cin, bpart, prev, x);

    // ---- recurrence ----
    for (int t = 0; t < TT; ++t) {
        step_gemms_kernel<<<dim3(4, 16, 8), 256, 0, stream>>>(
            x, hbuf, ctx, W_ih, W_hh, W_in, W_o1, b_in, b_o1, g6, cin, octx, t);
        gru_ln_kernel<<<256, 256, 0, stream>>>(g6, b_ih, b_hh, hbuf, ln_g, hg,
                                               mbuf, isbuf, t);
        kb_kernel<<<dim3(8, 16), 256, 0, stream>>>(hg, W_o1, uvv, octx, mbuf, isbuf, obuf);
        kc_kernel<<<256, 256, 0, stream>>>(obuf, Wo2t, b_o2, cin, bpart, x, prev, out, t);
    }
}

// Round 3
// 12334.151 us; speedup vs baseline: 1.4273x; 1.4273x over previous
//
#include <hip/hip_runtime.h>
#include <hip/hip_bf16.h>

// ---------------------------------------------------------------------------
// AutoregressiveBeamDecoder: B=256, T=128, D=512, H=1024, NB=64, HH=8
// Round 3: split-bf16 (hi+lo) MFMA GEMMs, fp32-equivalent accuracy.
//  C = Ahi@Whi + Ahi@Wlo + Alo@Whi  (3x mfma_f32_16x16x32_bf16, fp32 accum)
//  FIX vs round 2: B-tile LDS staging covered only 2048/4096 shorts
//  (single short8 per thread); now each thread stages 16 shorts (2x short8).
//  Uninitialized LDS had produced NaN -> fmaxf collapse -> all-zero output.
// ---------------------------------------------------------------------------

#define TS 68          // fp32 LDS row stride (fallback path)
#define LDP 40         // bf16 LDS row stride: 80 B -> 2-way bank aliasing max
constexpr int SZ = 262144;     // 256*1024
constexpr int TT = 128;        // T
constexpr int LDA_CTX = 65536; // T*D

typedef __attribute__((ext_vector_type(8))) short short8_t;
typedef __attribute__((ext_vector_type(4))) float f32x4;

// ---------------- bf16 split helpers (bit-level, RNE) ----------------------

__device__ __forceinline__ unsigned short f2bf_rne(float v) {
    unsigned u = __float_as_uint(v);
    unsigned r = u + 0x7fffu + ((u >> 16) & 1u);
    return (unsigned short)(r >> 16);
}
__device__ __forceinline__ float bfbits2f(unsigned short h) {
    return __uint_as_float(((unsigned)h) << 16);
}
__device__ __forceinline__ void split2(float v, unsigned short& h, unsigned short& l) {
    h = f2bf_rne(v);
    l = f2bf_rne(v - bfbits2f(h));
}

// ---------------- fp32 tiled GEMM core (setup + fallback) ------------------

__device__ __forceinline__ void gemm_tile64(
    const float* __restrict__ A, int lda, int Mlim, int b0,
    const float* __restrict__ W, int ldw, int n0, int K,
    float* At, float* Wt, float acc[4][4])
{
    const int tid = threadIdx.x;
    const int tx = tid & 15, ty = tid >> 4;
    const int r = tid >> 2, c0 = (tid & 3) << 2;
    for (int k0 = 0; k0 < K; k0 += 16) {
        float4 av = make_float4(0.f, 0.f, 0.f, 0.f);
        if (b0 + r < Mlim)
            av = *(const float4*)(A + (size_t)(b0 + r) * lda + k0 + c0);
        float4 wv = *(const float4*)(W + (size_t)(n0 + r) * ldw + k0 + c0);
        __syncthreads();
        At[(c0+0)*TS + r] = av.x; At[(c0+1)*TS + r] = av.y;
        At[(c0+2)*TS + r] = av.z; At[(c0+3)*TS + r] = av.w;
        Wt[(c0+0)*TS + r] = wv.x; Wt[(c0+1)*TS + r] = wv.y;
        Wt[(c0+2)*TS + r] = wv.z; Wt[(c0+3)*TS + r] = wv.w;
        __syncthreads();
#pragma unroll
        for (int kk = 0; kk < 16; ++kk) {
            float4 a = *(const float4*)(At + kk*TS + ty*4);
            float4 w = *(const float4*)(Wt + kk*TS + tx*4);
            acc[0][0] += a.x*w.x; acc[0][1] += a.x*w.y; acc[0][2] += a.x*w.z; acc[0][3] += a.x*w.w;
            acc[1][0] += a.y*w.x; acc[1][1] += a.y*w.y; acc[1][2] += a.y*w.z; acc[1][3] += a.y*w.w;
            acc[2][0] += a.z*w.x; acc[2][1] += a.z*w.y; acc[2][2] += a.z*w.z; acc[2][3] += a.z*w.w;
            acc[3][0] += a.w*w.x; acc[3][1] += a.w*w.y; acc[3][2] += a.w*w.z; acc[3][3] += a.w*w.w;
        }
    }
}

// -------------------- setup kernels ----------------------------------------

__global__ void pre0_kernel(const float* __restrict__ ctx, const int* __restrict__ bh,
                            const float* __restrict__ be, float* __restrict__ A0,
                            int* __restrict__ prev)
{
    int b = blockIdx.x, tid = threadIdx.x; // blockDim 512
    float s = 0.f;
    for (int t = 0; t < TT; ++t) s += ctx[(size_t)b * LDA_CTX + t * 512 + tid];
    A0[b * 1024 + tid] = s * (1.f / 128.f);
    float s2 = 0.f;
    for (int i = 0; i < 8; ++i) s2 += be[bh[b * 8 + i] * 512 + tid];
    A0[b * 1024 + 512 + tid] = s2 * 0.125f;
    if (tid == 0) prev[b] = bh[b * 8 + 7];
}

__global__ void copy_gb_kernel(const float* g, const float* bb, float* gb)
{
    int idx = blockIdx.x * 256 + threadIdx.x; // 8 blocks
    if (idx < 1024) gb[idx] = g[idx];
    else            gb[idx] = bb[idx - 1024];
}

__global__ void wo2t_kernel(const float* __restrict__ W_o2, float* __restrict__ Wo2t)
{
    int idx = blockIdx.x * 256 + threadIdx.x; // 256 blocks -> 65536
    int k = idx >> 6, n = idx & 63;
    Wo2t[idx] = W_o2[n * 1024 + k];
}

// split a weight sub-matrix [N x K] (src row stride src_ld, col offset col0)
__global__ void wsplit_kernel(const float* __restrict__ src, int src_ld, int col0,
                              int N, int K, unsigned short* __restrict__ hi,
                              unsigned short* __restrict__ lo)
{
    int idx = blockIdx.x * 256 + threadIdx.x;
    if (idx >= N * K) return;
    int n = idx / K, k = idx - n * K;
    float v = src[(size_t)n * src_ld + col0 + k];
    unsigned short h, l;
    split2(v, h, l);
    hi[idx] = h; lo[idx] = l;
}

// generic small fp32 GEMM (M may be < 64); act: 0 none, 1 tanh
__global__ void gemm64_kernel(const float* __restrict__ A, int lda, int M,
                              const float* __restrict__ W, int ldw, int K,
                              const float* __restrict__ bias,
                              float* __restrict__ C, int ldc, int act)
{
    __shared__ __align__(16) float At[16 * TS];
    __shared__ __align__(16) float Wt[16 * TS];
    float acc[4][4] = {};
    int b0 = blockIdx.x * 64, n0 = blockIdx.y * 64;
    gemm_tile64(A, lda, M, b0, W, ldw, n0, K, At, Wt, acc);
    int tx = threadIdx.x & 15, ty = threadIdx.x >> 4;
#pragma unroll
    for (int i = 0; i < 4; ++i) {
        int b = b0 + ty * 4 + i;
        if (b >= M) continue;
#pragma unroll
        for (int j = 0; j < 4; ++j) {
            int n = n0 + tx * 4 + j;
            float v = acc[i][j] + (bias ? bias[n] : 0.f);
            if (act == 1) v = tanhf(v);
            C[(size_t)b * ldc + n] = v;
        }
    }
}

__global__ void xbuild0_kernel(const float* __restrict__ cin0, const float* __restrict__ bpart,
                               const int* __restrict__ prev, float* __restrict__ x)
{
    int b = blockIdx.x, tid = threadIdx.x;
    int pb = prev[b];
    const float* cn = cin0 + (size_t)b * 1024;
    const float* bp = bpart + (size_t)pb * 1024;
#pragma unroll
    for (int jj = 0; jj < 4; ++jj) {
        int j = jj * 256 + tid;
        x[(size_t)b * 1024 + j] = fmaxf(cn[j] + bp[j], 0.f);
    }
}

// -------------------- per-step MFMA GEMM kernels ---------------------------
// block tile 64x128, 4 waves of 32x64 (2x4 frags of 16x16), BK=32

__global__ __launch_bounds__(256) void step_mfma_kernel(
    const float* __restrict__ x, const float* __restrict__ hBase,
    const float* __restrict__ ctx,
    const unsigned short* __restrict__ wih_hi, const unsigned short* __restrict__ wih_lo,
    const unsigned short* __restrict__ whh_hi, const unsigned short* __restrict__ whh_lo,
    const unsigned short* __restrict__ wcin_hi, const unsigned short* __restrict__ wcin_lo,
    const unsigned short* __restrict__ wo1c_hi, const unsigned short* __restrict__ wo1c_lo,
    const float* __restrict__ b_in, const float* __restrict__ b_o1,
    float* __restrict__ g6, float* __restrict__ cinBase, float* __restrict__ octx,
    int t)
{
    const int z = blockIdx.z;
    if (z == 6 && t + 1 >= TT) return;

    __shared__ __align__(16) unsigned short Ah[64 * LDP], Al[64 * LDP];
    __shared__ __align__(16) unsigned short Bh[128 * LDP], Bl[128 * LDP];

    const int tid = threadIdx.x;
    const int b0 = blockIdx.x * 64, n0 = blockIdx.y * 128;

    const float* A; int lda, K;
    const unsigned short *Whi, *Wlo;
    const float* bias = nullptr;
    float* C;
    if (z < 6) {
        int g = z % 3, s = z / 3;
        A = s ? (hBase + (size_t)(t & 1) * SZ) : x;
        lda = 1024; K = 1024;
        Whi = (s ? whh_hi : wih_hi) + (size_t)g * 1024 * 1024;
        Wlo = (s ? whh_lo : wih_lo) + (size_t)g * 1024 * 1024;
        C = g6 + (size_t)z * SZ;
    } else if (z == 6) {
        A = ctx + (size_t)(t + 1) * 512; lda = LDA_CTX; K = 512;
        Whi = wcin_hi; Wlo = wcin_lo; bias = b_in;
        C = cinBase + (size_t)((t + 1) & 1) * SZ;
    } else {
        A = ctx + (size_t)t * 512; lda = LDA_CTX; K = 512;
        Whi = wo1c_hi; Wlo = wo1c_lo; bias = b_o1;
        C = octx;
    }

    const int lane = tid & 63, wid = tid >> 6;
    const int wm = (wid >> 1) * 32, wn = (wid & 1) * 64;
    const int l15 = lane & 15, ko = (lane >> 4) * 8;
    const int brow = tid >> 1, bch = (tid & 1) << 4;

    f32x4 acc[2][4] = {};

    for (int k0 = 0; k0 < K; k0 += 32) {
        float4 av[2]; ushort4 ah[2], al[2];
#pragma unroll
        for (int i = 0; i < 2; ++i) {
            int idx = tid + i * 256;
            int row = idx >> 3, c4 = (idx & 7) << 2;
            av[i] = *(const float4*)(A + (size_t)(b0 + row) * lda + k0 + c4);
        }
        // B tile: 128 rows x 32 cols; 2 threads/row, 16 shorts (2x short8) each
        short8_t wh0 = *(const short8_t*)(Whi + (size_t)(n0 + brow) * K + k0 + bch);
        short8_t wh1 = *(const short8_t*)(Whi + (size_t)(n0 + brow) * K + k0 + bch + 8);
        short8_t wl0 = *(const short8_t*)(Wlo + (size_t)(n0 + brow) * K + k0 + bch);
        short8_t wl1 = *(const short8_t*)(Wlo + (size_t)(n0 + brow) * K + k0 + bch + 8);
#pragma unroll
        for (int i = 0; i < 2; ++i) {
            split2(av[i].x, ah[i].x, al[i].x);
            split2(av[i].y, ah[i].y, al[i].y);
            split2(av[i].z, ah[i].z, al[i].z);
            split2(av[i].w, ah[i].w, al[i].w);
        }
        __syncthreads();
#pragma unroll
        for (int i = 0; i < 2; ++i) {
            int idx = tid + i * 256;
            int row = idx >> 3, c4 = (idx & 7) << 2;
            *(ushort4*)&Ah[row * LDP + c4] = ah[i];
            *(ushort4*)&Al[row * LDP + c4] = al[i];
        }
        *(short8_t*)&Bh[brow * LDP + bch]     = wh0;
        *(short8_t*)&Bh[brow * LDP + bch + 8] = wh1;
        *(short8_t*)&Bl[brow * LDP + bch]     = wl0;
        *(short8_t*)&Bl[brow * LDP + bch + 8] = wl1;
        __syncthreads();

        short8_t afh[2], afl[2];
#pragma unroll
        for (int mi = 0; mi < 2; ++mi) {
            int ar = wm + mi * 16 + l15;
            afh[mi] = *(const short8_t*)&Ah[ar * LDP + ko];
            afl[mi] = *(const short8_t*)&Al[ar * LDP + ko];
        }
#pragma unroll
        for (int ni = 0; ni < 4; ++ni) {
            int br = wn + ni * 16 + l15;
            short8_t bh = *(const short8_t*)&Bh[br * LDP + ko];
            short8_t bl = *(const short8_t*)&Bl[br * LDP + ko];
#pragma unroll
            for (int mi = 0; mi < 2; ++mi) {
                acc[mi][ni] = __builtin_amdgcn_mfma_f32_16x16x32_bf16(afh[mi], bh, acc[mi][ni], 0, 0, 0);
                acc[mi][ni] = __builtin_amdgcn_mfma_f32_16x16x32_bf16(afh[mi], bl, acc[mi][ni], 0, 0, 0);
                acc[mi][ni] = __builtin_amdgcn_mfma_f32_16x16x32_bf16(afl[mi], bh, acc[mi][ni], 0, 0, 0);
            }
        }
    }

#pragma unroll
    for (int mi = 0; mi < 2; ++mi) {
#pragma unroll
        for (int ni = 0; ni < 4; ++ni) {
            int col = n0 + wn + ni * 16 + l15;
            float bv = bias ? bias[col] : 0.f;
#pragma unroll
            for (int r = 0; r < 4; ++r) {
                int row = b0 + wm + mi * 16 + (lane >> 4) * 4 + r;
                C[(size_t)row * 1024 + col] = acc[mi][ni][r] + bv;
            }
        }
    }
}

// o-GEMM (hg @ W_o1[:, :H]^T) with folded LN epilogue, MFMA version
__global__ __launch_bounds__(256) void kb_mfma_kernel(
    const float* __restrict__ hg,
    const unsigned short* __restrict__ w_hi, const unsigned short* __restrict__ w_lo,
    const float* __restrict__ uv, const float* __restrict__ octx,
    const float* __restrict__ mbuf, const float* __restrict__ isbuf,
    float* __restrict__ o)
{
    __shared__ __align__(16) unsigned short Ah[64 * LDP], Al[64 * LDP];
    __shared__ __align__(16) unsigned short Bh[128 * LDP], Bl[128 * LDP];

    const int tid = threadIdx.x;
    const int b0 = blockIdx.x * 64, n0 = blockIdx.y * 128;
    const int lane = tid & 63, wid = tid >> 6;
    const int wm = (wid >> 1) * 32, wn = (wid & 1) * 64;
    const int l15 = lane & 15, ko = (lane >> 4) * 8;
    const int brow = tid >> 1, bch = (tid & 1) << 4;

    f32x4 acc[2][4] = {};

    for (int k0 = 0; k0 < 1024; k0 += 32) {
        float4 av[2]; ushort4 ah[2], al[2];
#pragma unroll
        for (int i = 0; i < 2; ++i) {
            int idx = tid + i * 256;
            int row = idx >> 3, c4 = (idx & 7) << 2;
            av[i] = *(const float4*)(hg + (size_t)(b0 + row) * 1024 + k0 + c4);
        }
        short8_t wh0 = *(const short8_t*)(w_hi + (size_t)(n0 + brow) * 1024 + k0 + bch);
        short8_t wh1 = *(const short8_t*)(w_hi + (size_t)(n0 + brow) * 1024 + k0 + bch + 8);
        short8_t wl0 = *(const short8_t*)(w_lo + (size_t)(n0 + brow) * 1024 + k0 + bch);
        short8_t wl1 = *(const short8_t*)(w_lo + (size_t)(n0 + brow) * 1024 + k0 + bch + 8);
#pragma unroll
        for (int i = 0; i < 2; ++i) {
            split2(av[i].x, ah[i].x, al[i].x);
            split2(av[i].y, ah[i].y, al[i].y);
            split2(av[i].z, ah[i].z, al[i].z);
            split2(av[i].w, ah[i].w, al[i].w);
        }
        __syncthreads();
#pragma unroll
        for (int i = 0; i < 2; ++i) {
            int idx = tid + i * 256;
            int row = idx >> 3, c4 = (idx & 7) << 2;
            *(ushort4*)&Ah[row * LDP + c4] = ah[i];
            *(ushort4*)&Al[row * LDP + c4] = al[i];
        }
        *(short8_t*)&Bh[brow * LDP + bch]     = wh0;
        *(short8_t*)&Bh[brow * LDP + bch + 8] = wh1;
        *(short8_t*)&Bl[brow * LDP + bch]     = wl0;
        *(short8_t*)&Bl[brow * LDP + bch + 8] = wl1;
        __syncthreads();

        short8_t afh[2], afl[2];
#pragma unroll
        for (int mi = 0; mi < 2; ++mi) {
            int ar = wm + mi * 16 + l15;
            afh[mi] = *(const short8_t*)&Ah[ar * LDP + ko];
            afl[mi] = *(const short8_t*)&Al[ar * LDP + ko];
        }
#pragma unroll
        for (int ni = 0; ni < 4; ++ni) {
            int br = wn + ni * 16 + l15;
            short8_t bh = *(const short8_t*)&Bh[br * LDP + ko];
            short8_t bl = *(const short8_t*)&Bl[br * LDP + ko];
#pragma unroll
            for (int mi = 0; mi < 2; ++mi) {
                acc[mi][ni] = __builtin_amdgcn_mfma_f32_16x16x32_bf16(afh[mi], bh, acc[mi][ni], 0, 0, 0);
                acc[mi][ni] = __builtin_amdgcn_mfma_f32_16x16x32_bf16(afh[mi], bl, acc[mi][ni], 0, 0, 0);
                acc[mi][ni] = __builtin_amdgcn_mfma_f32_16x16x32_bf16(afl[mi], bh, acc[mi][ni], 0, 0, 0);
            }
        }
    }

#pragma unroll
    for (int mi = 0; mi < 2; ++mi) {
#pragma unroll
        for (int ni = 0; ni < 4; ++ni) {
            int col = n0 + wn + ni * 16 + l15;
            float u = uv[col], vb = uv[1024 + col];
#pragma unroll
            for (int r = 0; r < 4; ++r) {
                int row = b0 + wm + mi * 16 + (lane >> 4) * 4 + r;
                float m = mbuf[row], is = isbuf[row];
                float v = (acc[mi][ni][r] - m * u) * is + vb + octx[(size_t)row * 1024 + col];
                o[(size_t)row * 1024 + col] = fmaxf(v, 0.f);
            }
        }
    }
}

// -------------------- fallback fp32 step kernels (round 1) -----------------

__global__ void step_gemms_kernel(
    const float* __restrict__ x, const float* __restrict__ hBase,
    const float* __restrict__ ctx,
    const float* __restrict__ Wih, const float* __restrict__ Whh,
    const float* __restrict__ Win, const float* __restrict__ Wo1,
    const float* __restrict__ b_in, const float* __restrict__ b_o1,
    float* __restrict__ g6, float* __restrict__ cinBase, float* __restrict__ octx,
    int t)
{
    __shared__ __align__(16) float At[16 * TS];
    __shared__ __align__(16) float Wt[16 * TS];
    float acc[4][4] = {};
    const int z = blockIdx.z, b0 = blockIdx.x * 64, n0 = blockIdx.y * 64;
    const float *A, *W, *bias = nullptr;
    float* C;
    int lda, ldw, K;
    if (z < 6) {
        int g = z % 3, s = z / 3;
        A = s ? (hBase + (size_t)(t & 1) * SZ) : x;
        lda = 1024;
        W = (s ? Whh : Wih) + (size_t)(g * 1024) * 1024;
        ldw = 1024; K = 1024;
        C = g6 + (size_t)z * SZ;
    } else if (z == 6) {
        if (t + 1 >= TT) return;
        A = ctx + (size_t)(t + 1) * 512; lda = LDA_CTX;
        W = Win; ldw = 1024; K = 512; bias = b_in;
        C = cinBase + (size_t)((t + 1) & 1) * SZ;
    } else {
        A = ctx + (size_t)t * 512; lda = LDA_CTX;
        W = Wo1 + 1024; ldw = 1536; K = 512; bias = b_o1;
        C = octx;
    }
    gemm_tile64(A, lda, 256, b0, W, ldw, n0, K, At, Wt, acc);
    int tx = threadIdx.x & 15, ty = threadIdx.x >> 4;
#pragma unroll
    for (int i = 0; i < 4; ++i) {
        int b = b0 + ty * 4 + i;
#pragma unroll
        for (int j = 0; j < 4; ++j) {
            int n = n0 + tx * 4 + j;
            float v = acc[i][j];
            if (bias) v += bias[n];
            C[(size_t)b * 1024 + n] = v;
        }
    }
}

__global__ void kb_kernel(const float* __restrict__ hg, const float* __restrict__ Wo1,
                          const float* __restrict__ uv, const float* __restrict__ octx,
                          const float* __restrict__ mbuf, const float* __restrict__ isbuf,
                          float* __restrict__ o)
{
    __shared__ __align__(16) float At[16 * TS];
    __shared__ __align__(16) float Wt[16 * TS];
    float acc[2][4] = {};
    const int b0 = blockIdx.x * 32, n0 = blockIdx.y * 64;
    const int tid = threadIdx.x, tx = tid & 15, ty = tid >> 4;
    const int r = tid >> 2, c0 = (tid & 3) << 2;
    for (int k0 = 0; k0 < 1024; k0 += 16) {
        float4 av = make_float4(0.f, 0.f, 0.f, 0.f);
        if (r < 32) av = *(const float4*)(hg + (size_t)(b0 + r) * 1024 + k0 + c0);
        float4 wv = *(const float4*)(Wo1 + (size_t)(n0 + r) * 1536 + k0 + c0);
        __syncthreads();
        At[(c0+0)*TS + r] = av.x; At[(c0+1)*TS + r] = av.y;
        At[(c0+2)*TS + r] = av.z; At[(c0+3)*TS + r] = av.w;
        Wt[(c0+0)*TS + r] = wv.x; Wt[(c0+1)*TS + r] = wv.y;
        Wt[(c0+2)*TS + r] = wv.z; Wt[(c0+3)*TS + r] = wv.w;
        __syncthreads();
#pragma unroll
        for (int kk = 0; kk < 16; ++kk) {
            float2 a = *(const float2*)(At + kk*TS + ty*2);
            float4 w = *(const float4*)(Wt + kk*TS + tx*4);
            acc[0][0] += a.x*w.x; acc[0][1] += a.x*w.y; acc[0][2] += a.x*w.z; acc[0][3] += a.x*w.w;
            acc[1][0] += a.y*w.x; acc[1][1] += a.y*w.y; acc[1][2] += a.y*w.z; acc[1][3] += a.y*w.w;
        }
    }
#pragma unroll
    for (int i = 0; i < 2; ++i) {
        int b = b0 + ty * 2 + i;
        float m = mbuf[b], is = isbuf[b];
#pragma unroll
        for (int j = 0; j < 4; ++j) {
            int n = n0 + tx * 4 + j;
            float v = (acc[i][j] - m * uv[n]) * is + uv[1024 + n] + octx[(size_t)b * 1024 + n];
            o[(size_t)b * 1024 + n] = fmaxf(v, 0.f);
        }
    }
}

// -------------------- shared per-step kernels ------------------------------

__global__ void gru_ln_kernel(const float* __restrict__ g6,
                              const float* __restrict__ b_ih, const float* __restrict__ b_hh,
                              float* __restrict__ hBase, const float* __restrict__ ln_g,
                              float* __restrict__ hg, float* __restrict__ mbuf,
                              float* __restrict__ isbuf, int t)
{
    __shared__ float rs[256], rq[256];
    int b = blockIdx.x, tid = threadIdx.x;
    const float* hc = hBase + (size_t)(t & 1) * SZ + (size_t)b * 1024;
    float* hnx = hBase + (size_t)((t + 1) & 1) * SZ + (size_t)b * 1024;
    float s = 0.f, q = 0.f;
#pragma unroll
    for (int jj = 0; jj < 4; ++jj) {
        int j = jj * 256 + tid;
        size_t base = (size_t)b * 1024 + j;
        float xr = g6[0 * (size_t)SZ + base] + b_ih[j];
        float xz = g6[1 * (size_t)SZ + base] + b_ih[1024 + j];
        float xn = g6[2 * (size_t)SZ + base] + b_ih[2048 + j];
        float hr = g6[3 * (size_t)SZ + base] + b_hh[j];
        float hz = g6[4 * (size_t)SZ + base] + b_hh[1024 + j];
        float hn = g6[5 * (size_t)SZ + base] + b_hh[2048 + j];
        float r = 1.f / (1.f + expf(-(xr + hr)));
        float z = 1.f / (1.f + expf(-(xz + hz)));
        float nn = tanhf(xn + r * hn);
        float ho = hc[j];
        float hv = (1.f - z) * nn + z * ho;
        hnx[j] = hv;
        hg[base] = hv * ln_g[j];
        s += hv; q += hv * hv;
    }
    rs[tid] = s; rq[tid] = q;
    __syncthreads();
    for (int st = 128; st; st >>= 1) {
        if (tid < st) { rs[tid] += rs[tid + st]; rq[tid] += rq[tid + st]; }
        __syncthreads();
    }
    if (tid == 0) {
        float m = rs[0] * (1.f / 1024.f);
        float var = rq[0] * (1.f / 1024.f) - m * m;
        mbuf[b] = m;
        isbuf[b] = rsqrtf(var + 1e-5f);
    }
}

__global__ void kc_kernel(const float* __restrict__ o, const float* __restrict__ Wo2t,
                          const float* __restrict__ b_o2, const float* __restrict__ cinBase,
                          const float* __restrict__ bpart, float* __restrict__ x,
                          int* __restrict__ prev, float* __restrict__ out, int t)
{
    __shared__ __align__(16) float os[1024];
    __shared__ float red[4][64];
    __shared__ int sidx;
    int b = blockIdx.x, tid = threadIdx.x;
    const float* orow = o + (size_t)b * 1024;
    *(float4*)&os[tid * 4] = *(const float4*)&orow[tid * 4];
    __syncthreads();
    int n = tid & 63, seg = tid >> 6;
    float p = 0.f;
    int k0 = seg * 256;
#pragma unroll 8
    for (int k = 0; k < 256; ++k) p += os[k0 + k] * Wo2t[(size_t)(k0 + k) * 64 + n];
    red[seg][n] = p;
    __syncthreads();
    if (tid < 64) {
        float lg = red[0][tid] + red[1][tid] + red[2][tid] + red[3][tid] + b_o2[tid];
        out[((size_t)b * TT + t) * 64 + tid] = lg;
        float v = lg; int idx = tid;
        for (int off = 32; off; off >>= 1) {
            float ov = __shfl_xor(v, off);
            int oi = __shfl_xor(idx, off);
            if (ov > v || (ov == v && oi < idx)) { v = ov; idx = oi; }
        }
        if (tid == 0) { prev[b] = idx; sidx = idx; }
    }
    __syncthreads();
    if (t + 1 < TT) {
        int pb = sidx;
        const float* cn = cinBase + (size_t)((t + 1) & 1) * SZ + (size_t)b * 1024;
        const float* bp = bpart + (size_t)pb * 1024;
#pragma unroll
        for (int jj = 0; jj < 4; ++jj) {
            int j = jj * 256 + tid;
            x[(size_t)b * 1024 + j] = fmaxf(cn[j] + bp[j], 0.f);
        }
    }
}

// ---------------------------------------------------------------------------

extern "C" void kernel_launch(void* const* d_in, const int* in_sizes, int n_in,
                              void* d_out, int out_size, void* d_ws, size_t ws_size,
                              hipStream_t stream)
{
    const float* ctx    = (const float*)d_in[0];
    const int*   bh     = (const int*)d_in[1];
    const float* be     = (const float*)d_in[2];
    const float* W_in   = (const float*)d_in[3];
    const float* b_in   = (const float*)d_in[4];
    const float* W_init = (const float*)d_in[5];
    const float* b_init = (const float*)d_in[6];
    const float* W_ih   = (const float*)d_in[7];
    const float* b_ih   = (const float*)d_in[8];
    const float* W_hh   = (const float*)d_in[9];
    const float* b_hh   = (const float*)d_in[10];
    const float* ln_g   = (const float*)d_in[11];
    const float* ln_b   = (const float*)d_in[12];
    const float* W_o1   = (const float*)d_in[13];
    const float* b_o1   = (const float*)d_in[14];
    const float* W_o2   = (const float*)d_in[15];
    const float* b_o2   = (const float*)d_in[16];
    float* out = (float*)d_out;
    float* ws  = (float*)d_ws;

    // fp32 region
    float* A0    = ws;                      // 256x1024
    float* hbuf  = ws + 262144;             // 2 slots
    float* hg    = ws + 786432;
    float* x     = ws + 1048576;
    float* cin   = ws + 1310720;            // 2 slots
    float* octx  = ws + 1835008;
    float* g6    = ws + 2097152;            // 6 slots
    float* obuf  = ws + 3670016;
    float* bpart = ws + 3932160;            // 64x1024
    float* uvv   = ws + 3997696;            // 2x1024
    float* gb    = ws + 3999744;            // 2x1024
    float* Wo2t  = ws + 4001792;            // 1024x64
    float* mbuf  = ws + 4067328;            // 256
    float* isbuf = ws + 4067584;            // 256
    int*   prev  = (int*)(ws + 4067840);    // 256
    // bf16 split-weight region
    unsigned short* bf = (unsigned short*)(ws + 4068096);
    unsigned short* wih_hi  = bf;
    unsigned short* wih_lo  = bf + 3145728;
    unsigned short* whh_hi  = bf + 6291456;
    unsigned short* whh_lo  = bf + 9437184;
    unsigned short* wo1k_hi = bf + 12582912;
    unsigned short* wo1k_lo = bf + 13631488;
    unsigned short* wo1c_hi = bf + 14680064;
    unsigned short* wo1c_lo = bf + 15204352;
    unsigned short* wcin_hi = bf + 15728640;
    unsigned short* wcin_lo = bf + 16252928;

    const bool mfma_path = (ws_size >= 49830000ull);

    // ---- setup (shared) ----
    pre0_kernel<<<256, 512, 0, stream>>>(ctx, bh, be, A0, prev);
    copy_gb_kernel<<<8, 256, 0, stream>>>(ln_g, ln_b, gb);
    wo2t_kernel<<<256, 256, 0, stream>>>(W_o2, Wo2t);
    gemm64_kernel<<<dim3(4, 16), 256, 0, stream>>>(A0, 1024, 256, W_init, 1024, 1024,
                                                   b_init, hbuf, 1024, 1);
    gemm64_kernel<<<dim3(1, 16), 256, 0, stream>>>(be, 512, 64, W_in + 512, 1024, 512,
                                                   nullptr, bpart, 1024, 0);
    gemm64_kernel<<<dim3(1, 16), 256, 0, stream>>>(gb, 1024, 2, W_o1, 1536, 1024,
                                                   nullptr, uvv, 1024, 0);
    gemm64_kernel<<<dim3(4, 16), 256, 0, stream>>>(ctx, LDA_CTX, 256, W_in, 1024, 512,
                                                   b_in, cin, 1024, 0);
    xbuild0_kernel<<<256, 256, 0, stream>>>(cin, bpart, prev, x);

    if (mfma_path) {
        wsplit_kernel<<<12288, 256, 0, stream>>>(W_ih, 1024, 0, 3072, 1024, wih_hi, wih_lo);
        wsplit_kernel<<<12288, 256, 0, stream>>>(W_hh, 1024, 0, 3072, 1024, whh_hi, whh_lo);
        wsplit_kernel<<<4096, 256, 0, stream>>>(W_o1, 1536, 0, 1024, 1024, wo1k_hi, wo1k_lo);
        wsplit_kernel<<<2048, 256, 0, stream>>>(W_o1, 1536, 1024, 1024, 512, wo1c_hi, wo1c_lo);
        wsplit_kernel<<<2048, 256, 0, stream>>>(W_in, 1024, 0, 1024, 512, wcin_hi, wcin_lo);

        for (int t = 0; t < TT; ++t) {
            step_mfma_kernel<<<dim3(4, 8, 8), 256, 0, stream>>>(
                x, hbuf, ctx, wih_hi, wih_lo, whh_hi, whh_lo, wcin_hi, wcin_lo,
                wo1c_hi, wo1c_lo, b_in, b_o1, g6, cin, octx, t);
            gru_ln_kernel<<<256, 256, 0, stream>>>(g6, b_ih, b_hh, hbuf, ln_g, hg,
                                                   mbuf, isbuf, t);
            kb_mfma_kernel<<<dim3(4, 8), 256, 0, stream>>>(hg, wo1k_hi, wo1k_lo, uvv,
                                                           octx, mbuf, isbuf, obuf);
            kc_kernel<<<256, 256, 0, stream>>>(obuf, Wo2t, b_o2, cin, bpart, x, prev, out, t);
        }
    } else {
        for (int t = 0; t < TT; ++t) {
            step_gemms_kernel<<<dim3(4, 16, 8), 256, 0, stream>>>(
                x, hbuf, ctx, W_ih, W_hh, W_in, W_o1, b_in, b_o1, g6, cin, octx, t);
            gru_ln_kernel<<<256, 256, 0, stream>>>(g6, b_ih, b_hh, hbuf, ln_g, hg,
                                                   mbuf, isbuf, t);
            kb_kernel<<<dim3(8, 16), 256, 0, stream>>>(hg, W_o1, uvv, octx, mbuf, isbuf, obuf);
            kc_kernel<<<256, 256, 0, stream>>>(obuf, Wo2t, b_o2, cin, bpart, x, prev, out, t);
        }
    }
}